// Round 1
// baseline (539.860 us; speedup 1.0000x reference)
//
#include <hip/hip_runtime.h>

typedef __attribute__((ext_vector_type(8))) short short8;
typedef __attribute__((ext_vector_type(4))) float f32x4;

#define NTOK   8192
#define DDIM   1024
#define ENUM   16
#define FDIM   768
#define NSLOT  16384

// ---------- ws layout (bytes) ----------
#define WS_TOPK_IDX 0           // int[16384]
#define WS_TOPK_W   65536       // float[16384]
#define WS_ROWS     131072      // int[16384]  grouped slot list
#define WS_ROW_OF   196608      // int[16384]  slot -> grouped row
#define WS_COUNTS   262144      // int[16]
#define WS_PROB     262208      // float[16]
#define WS_OFFSETS  262272      // int[17]
#define WS_XBF      1048576     // bf16[8192][1024]   16 MB
#define WS_H        17825792    // bf16[16384][768]   24 MB
#define WS_O        42991616    // f32 [16384][1024]  64 MB

__device__ __forceinline__ unsigned short f2bf(float f) {
  union { float f; unsigned int u; } v; v.f = f;
  unsigned int r = v.u + 0x7fffu + ((v.u >> 16) & 1u);
  return (unsigned short)(r >> 16);
}
__device__ __forceinline__ float bf2f(unsigned short s) {
  union { unsigned int u; float f; } v; v.u = ((unsigned int)s) << 16;
  return v.f;
}

// ---------------- 1. hidden fp32 -> bf16 ----------------
__global__ void k_convert_x(const float* __restrict__ x, unsigned short* __restrict__ xb) {
  int i = blockIdx.x * blockDim.x + threadIdx.x;     // exactly 2097152 float4s
  float4 v = ((const float4*)x)[i];
  ushort4 o;
  o.x = f2bf(v.x); o.y = f2bf(v.y); o.z = f2bf(v.z); o.w = f2bf(v.w);
  ((ushort4*)xb)[i] = o;
}

// ---------------- 2. router ----------------
// one wave per 4 tokens; lane e = lane&15, quarter q = lane>>4 covers 256 d's.
__global__ __launch_bounds__(256) void k_router(
    const float* __restrict__ X, const float* __restrict__ Wr,
    int* __restrict__ topk_idx, float* __restrict__ topk_w,
    int* __restrict__ counts, float* __restrict__ prob_sum)
{
  int tid = threadIdx.x, lane = tid & 63, wid = tid >> 6;
  int wave_global = blockIdx.x * 4 + wid;            // 2048 waves
  int q = lane >> 4, e = lane & 15;
  float pacc = 0.f; int cacc = 0;

  for (int i = 0; i < 4; i++) {
    int t = wave_global * 4 + i;
    const float* x = X + (size_t)t * DDIM + q * 256;
    const float* w = Wr + q * 256 * ENUM + e;
    double acc = 0.0;                                // double acc: match np top-k ties
    #pragma unroll 4
    for (int j = 0; j < 256; j++) acc += (double)x[j] * (double)w[j * ENUM];
    acc += __shfl_xor(acc, 16, 64);
    acc += __shfl_xor(acc, 32, 64);
    float logit = (float)acc;

    float m = logit;
    for (int d = 1; d < 16; d <<= 1) m = fmaxf(m, __shfl_xor(m, d, 64));
    float p = expf(logit - m);
    float s = p;
    for (int d = 1; d < 16; d <<= 1) s += __shfl_xor(s, d, 64);
    p = p / s;

    float p1 = p; int e1 = e;
    for (int d = 1; d < 16; d <<= 1) {
      float op = __shfl_xor(p1, d, 64); int oe = __shfl_xor(e1, d, 64);
      if (op > p1 || (op == p1 && oe < e1)) { p1 = op; e1 = oe; }
    }
    float px = (e == e1) ? -1.f : p;
    float p2 = px; int e2 = e;
    for (int d = 1; d < 16; d <<= 1) {
      float op = __shfl_xor(p2, d, 64); int oe = __shfl_xor(e2, d, 64);
      if (op > p2 || (op == p2 && oe < e2)) { p2 = op; e2 = oe; }
    }
    float den = fmaxf(p1 + p2, 1e-9f);
    if (lane == 0) {
      topk_idx[2 * t]     = e1; topk_idx[2 * t + 1] = e2;
      topk_w[2 * t]       = p1 / den; topk_w[2 * t + 1] = p2 / den;
    }
    if (lane < 16) { pacc += p; cacc += (e1 == e) + (e2 == e); }
  }
  __shared__ float sp[16]; __shared__ int sc[16];
  if (tid < 16) { sp[tid] = 0.f; sc[tid] = 0; }
  __syncthreads();
  if (lane < 16) { atomicAdd(&sp[e], pacc); atomicAdd(&sc[e], cacc); }
  __syncthreads();
  if (tid < 16) { atomicAdd(&prob_sum[tid], sp[tid]); atomicAdd(&counts[tid], sc[tid]); }
}

// ---------------- 3. deterministic per-expert slot lists ----------------
__global__ __launch_bounds__(256) void k_build_lists(
    const int* __restrict__ topk_idx, const int* __restrict__ counts,
    int* __restrict__ offsets, int* __restrict__ rows, int* __restrict__ row_of)
{
  int e = blockIdx.x;
  int base = 0;
  for (int i = 0; i < e; i++) base += counts[i];
  if (threadIdx.x == 0) {
    offsets[e] = base;
    if (e == 15) offsets[16] = base + counts[15];
  }
  __shared__ int wave_tot[4];
  int lane = threadIdx.x & 63, wid = threadIdx.x >> 6;
  int running = 0;
  for (int chunk = 0; chunk < NSLOT; chunk += 256) {
    int s = chunk + threadIdx.x;
    bool match = (topk_idx[s] == e);
    unsigned long long mask = __ballot(match);
    int wpre = __popcll(mask & ((1ull << lane) - 1ull));
    if (lane == 0) wave_tot[wid] = __popcll(mask);
    __syncthreads();
    int prefix = running;
    for (int w = 0; w < wid; w++) prefix += wave_tot[w];
    if (match) { int pos = base + prefix + wpre; rows[pos] = s; row_of[s] = pos; }
    running += wave_tot[0] + wave_tot[1] + wave_tot[2] + wave_tot[3];
    __syncthreads();
  }
}

// ---------------- 4. fused gate+up grouped GEMM ----------------
// tile 128(M) x 128(N of F) x 64(K of D); 8 waves (2m x 4n); wave tile 64x32
__global__ __launch_bounds__(512) void k_gateup(
    const unsigned short* __restrict__ Xbf, const float* __restrict__ Wg,
    const float* __restrict__ Wu, const int* __restrict__ counts,
    const int* __restrict__ offsets, const int* __restrict__ rows,
    unsigned short* __restrict__ H)
{
  const int e = blockIdx.z;
  const int cnt = counts[e];
  const int mt = blockIdx.y;
  if (mt * 128 >= cnt) return;
  const int nt = blockIdx.x;                 // 0..5
  const int base = offsets[e];

  __shared__ __align__(16) unsigned char sA[128 * 64 * 2];
  __shared__ __align__(16) unsigned char sBg[128 * 64 * 2];
  __shared__ __align__(16) unsigned char sBu[128 * 64 * 2];
  __shared__ int sTok[128];

  const int tid = threadIdx.x;
  const int lane = tid & 63;
  const int wid = tid >> 6;
  const int wm = wid >> 2, wn = wid & 3;
  const int q = lane >> 4, c = lane & 15;

  if (tid < 128) {
    int r = mt * 128 + tid;
    if (r >= cnt) r = cnt - 1;
    sTok[tid] = rows[base + r];              // slot id (token = slot>>1)
  }
  __syncthreads();

  const float* wgBase = Wg + (size_t)e * DDIM * FDIM + nt * 128;
  const float* wuBase = Wu + (size_t)e * DDIM * FDIM + nt * 128;

  f32x4 accg[4][2], accu[4][2];
  #pragma unroll
  for (int i = 0; i < 4; i++)
    #pragma unroll
    for (int j = 0; j < 2; j++) { accg[i][j] = (f32x4)(0.f); accu[i][j] = (f32x4)(0.f); }

  for (int kt = 0; kt < DDIM / 64; kt++) {
    // stage A (gathered rows of Xbf), XOR-swizzled
    #pragma unroll
    for (int p = 0; p < 2; p++) {
      int o = tid + 512 * p;
      int row = o >> 3, col8 = (o & 7) * 8;
      int tok = sTok[row] >> 1;
      uint4 v = *(const uint4*)(Xbf + (size_t)tok * DDIM + kt * 64 + col8);
      *(uint4*)(sA + ((row * 128 + col8 * 2) ^ ((row & 7) << 4))) = v;
    }
    // stage B transposed ([n][k], K-contiguous): per-k scalar loads, coalesced over n
    {
      int n = tid & 127;
      int swz = (n & 7) << 4;
      #pragma unroll
      for (int p = 0; p < 2; p++) {
        int k0 = ((tid >> 7) << 3) + 32 * p;
        const float* sg = wgBase + (size_t)(kt * 64 + k0) * FDIM + n;
        const float* su = wuBase + (size_t)(kt * 64 + k0) * FDIM + n;
        union { unsigned short s[8]; uint4 v; } ug, uu;
        #pragma unroll
        for (int j = 0; j < 8; j++) {
          ug.s[j] = f2bf(sg[(size_t)j * FDIM]);
          uu.s[j] = f2bf(su[(size_t)j * FDIM]);
        }
        int b = (n * 128 + k0 * 2) ^ swz;
        *(uint4*)(sBg + b) = ug.v;
        *(uint4*)(sBu + b) = uu.v;
      }
    }
    __syncthreads();
    #pragma unroll
    for (int kk = 0; kk < 2; kk++) {
      short8 af[4];
      #pragma unroll
      for (int mf = 0; mf < 4; mf++) {
        int row = wm * 64 + mf * 16 + c;
        af[mf] = *(const short8*)(sA + ((row * 128 + kk * 64 + q * 16) ^ ((row & 7) << 4)));
      }
      #pragma unroll
      for (int nf = 0; nf < 2; nf++) {
        int col = wn * 32 + nf * 16 + c;
        int b = (col * 128 + kk * 64 + q * 16) ^ ((col & 7) << 4);
        short8 bg = *(const short8*)(sBg + b);
        short8 bu = *(const short8*)(sBu + b);
        #pragma unroll
        for (int mf = 0; mf < 4; mf++) {
          accg[mf][nf] = __builtin_amdgcn_mfma_f32_16x16x32_bf16(af[mf], bg, accg[mf][nf], 0, 0, 0);
          accu[mf][nf] = __builtin_amdgcn_mfma_f32_16x16x32_bf16(af[mf], bu, accu[mf][nf], 0, 0, 0);
        }
      }
    }
    __syncthreads();
  }
  // epilogue: H = silu(g) * u  (C layout: col=lane&15, row=(lane>>4)*4+reg)
  #pragma unroll
  for (int mf = 0; mf < 4; mf++)
    #pragma unroll
    for (int nf = 0; nf < 2; nf++)
      #pragma unroll
      for (int r = 0; r < 4; r++) {
        int row = wm * 64 + mf * 16 + q * 4 + r;
        int gr = mt * 128 + row;
        if (gr < cnt) {
          int col = wn * 32 + nf * 16 + c;
          float g = accg[mf][nf][r], u = accu[mf][nf][r];
          float sv = g / (1.0f + __expf(-g));
          H[(size_t)(base + gr) * FDIM + nt * 128 + col] = f2bf(sv * u);
        }
      }
}

// ---------------- 5. down grouped GEMM -> O (fp32) ----------------
__global__ __launch_bounds__(512) void k_down(
    const unsigned short* __restrict__ H, const float* __restrict__ Wd,
    const int* __restrict__ counts, const int* __restrict__ offsets,
    float* __restrict__ O)
{
  const int e = blockIdx.z;
  const int cnt = counts[e];
  const int mt = blockIdx.y;
  if (mt * 128 >= cnt) return;
  const int nt = blockIdx.x;                 // 0..7
  const int base = offsets[e];

  __shared__ __align__(16) unsigned char sA[128 * 64 * 2];
  __shared__ __align__(16) unsigned char sB[128 * 64 * 2];

  const int tid = threadIdx.x;
  const int lane = tid & 63;
  const int wid = tid >> 6;
  const int wm = wid >> 2, wn = wid & 3;
  const int q = lane >> 4, c = lane & 15;

  const float* wdBase = Wd + (size_t)e * FDIM * DDIM + nt * 128;

  f32x4 acc[4][2];
  #pragma unroll
  for (int i = 0; i < 4; i++)
    #pragma unroll
    for (int j = 0; j < 2; j++) acc[i][j] = (f32x4)(0.f);

  for (int kt = 0; kt < FDIM / 64; kt++) {
    #pragma unroll
    for (int p = 0; p < 2; p++) {
      int o = tid + 512 * p;
      int row = o >> 3, col8 = (o & 7) * 8;
      int gr = base + mt * 128 + row;
      if (gr > NSLOT - 1) gr = NSLOT - 1;
      uint4 v = *(const uint4*)(H + (size_t)gr * FDIM + kt * 64 + col8);
      *(uint4*)(sA + ((row * 128 + col8 * 2) ^ ((row & 7) << 4))) = v;
    }
    {
      int n = tid & 127;
      int swz = (n & 7) << 4;
      #pragma unroll
      for (int p = 0; p < 2; p++) {
        int k0 = ((tid >> 7) << 3) + 32 * p;
        const float* sd = wdBase + (size_t)(kt * 64 + k0) * DDIM + n;
        union { unsigned short s[8]; uint4 v; } ud;
        #pragma unroll
        for (int j = 0; j < 8; j++) ud.s[j] = f2bf(sd[(size_t)j * DDIM]);
        *(uint4*)(sB + ((n * 128 + k0 * 2) ^ swz)) = ud.v;
      }
    }
    __syncthreads();
    #pragma unroll
    for (int kk = 0; kk < 2; kk++) {
      short8 af[4];
      #pragma unroll
      for (int mf = 0; mf < 4; mf++) {
        int row = wm * 64 + mf * 16 + c;
        af[mf] = *(const short8*)(sA + ((row * 128 + kk * 64 + q * 16) ^ ((row & 7) << 4)));
      }
      #pragma unroll
      for (int nf = 0; nf < 2; nf++) {
        int col = wn * 32 + nf * 16 + c;
        short8 bf = *(const short8*)(sB + ((col * 128 + kk * 64 + q * 16) ^ ((col & 7) << 4)));
        #pragma unroll
        for (int mf = 0; mf < 4; mf++)
          acc[mf][nf] = __builtin_amdgcn_mfma_f32_16x16x32_bf16(af[mf], bf, acc[mf][nf], 0, 0, 0);
      }
    }
    __syncthreads();
  }
  #pragma unroll
  for (int mf = 0; mf < 4; mf++)
    #pragma unroll
    for (int nf = 0; nf < 2; nf++)
      #pragma unroll
      for (int r = 0; r < 4; r++) {
        int row = wm * 64 + mf * 16 + q * 4 + r;
        int gr = mt * 128 + row;
        if (gr < cnt) {
          int col = wn * 32 + nf * 16 + c;
          O[(size_t)(base + gr) * DDIM + nt * 128 + col] = acc[mf][nf][r];
        }
      }
}

// ---------------- 6. combine top-2 ----------------
__global__ __launch_bounds__(256) void k_combine(
    const float* __restrict__ O, const int* __restrict__ row_of,
    const float* __restrict__ topk_w, float* __restrict__ out)
{
  int t = blockIdx.x;
  int r0 = row_of[2 * t], r1 = row_of[2 * t + 1];
  float w0 = topk_w[2 * t], w1 = topk_w[2 * t + 1];
  int d = threadIdx.x * 4;
  float4 a = *(const float4*)(O + (size_t)r0 * DDIM + d);
  float4 b = *(const float4*)(O + (size_t)r1 * DDIM + d);
  float4 o;
  o.x = w0 * a.x + w1 * b.x; o.y = w0 * a.y + w1 * b.y;
  o.z = w0 * a.z + w1 * b.z; o.w = w0 * a.w + w1 * b.w;
  *(float4*)(out + (size_t)t * DDIM + d) = o;
}

// ---------------- 7. aux loss ----------------
__global__ void k_aux(const int* __restrict__ counts, const float* __restrict__ prob_sum,
                      float* __restrict__ out_aux) {
  if (threadIdx.x == 0) {
    float s = 0.f;
    for (int e = 0; e < ENUM; e++)
      s += ((float)counts[e] / (float)NTOK) * (prob_sum[e] / (float)NTOK);
    out_aux[0] = 0.001f * (float)ENUM * s;
  }
}

extern "C" void kernel_launch(void* const* d_in, const int* in_sizes, int n_in,
                              void* d_out, int out_size, void* d_ws, size_t ws_size,
                              hipStream_t stream) {
  const float* X  = (const float*)d_in[0];
  const float* Wg = (const float*)d_in[1];
  const float* Wu = (const float*)d_in[2];
  const float* Wd = (const float*)d_in[3];
  const float* Wr = (const float*)d_in[4];
  float* out = (float*)d_out;

  char* ws = (char*)d_ws;
  int*   topk_idx = (int*)(ws + WS_TOPK_IDX);
  float* topk_w   = (float*)(ws + WS_TOPK_W);
  int*   rows     = (int*)(ws + WS_ROWS);
  int*   row_of   = (int*)(ws + WS_ROW_OF);
  int*   counts   = (int*)(ws + WS_COUNTS);
  float* prob_sum = (float*)(ws + WS_PROB);
  int*   offsets  = (int*)(ws + WS_OFFSETS);
  unsigned short* Xbf = (unsigned short*)(ws + WS_XBF);
  unsigned short* H   = (unsigned short*)(ws + WS_H);
  float* O            = (float*)(ws + WS_O);

  hipMemsetAsync(ws + WS_COUNTS, 0, 128, stream);   // counts + prob_sum
  k_convert_x<<<8192, 256, 0, stream>>>(X, Xbf);
  k_router<<<512, 256, 0, stream>>>(X, Wr, topk_idx, topk_w, counts, prob_sum);
  k_build_lists<<<16, 256, 0, stream>>>(topk_idx, counts, offsets, rows, row_of);
  k_gateup<<<dim3(6, 64, 16), 512, 0, stream>>>(Xbf, Wg, Wu, counts, offsets, rows, H);
  k_down<<<dim3(8, 64, 16), 512, 0, stream>>>(H, Wd, counts, offsets, O);
  k_combine<<<8192, 256, 0, stream>>>(O, row_of, topk_w, out);
  k_aux<<<1, 64, 0, stream>>>(counts, prob_sum, out + (size_t)NTOK * DDIM);
}

// Round 2
// 328.665 us; speedup vs baseline: 1.6426x; 1.6426x over previous
//
#include <hip/hip_runtime.h>

typedef __attribute__((ext_vector_type(8))) short short8;
typedef __attribute__((ext_vector_type(4))) float f32x4;

#define NTOK   8192
#define DDIM   1024
#define ENUM   16
#define FDIM   768
#define NSLOT  16384

// ---------- ws layout (bytes) ----------
#define WS_TOPK_IDX 0           // int[16384]
#define WS_TOPK_W   65536       // float[16384]
#define WS_ROWS     131072      // int[16384]
#define WS_ROW_OF   196608      // int[16384]
#define WS_COUNTS   262144      // int[16]
#define WS_PROB     262208      // float[16]
#define WS_OFFSETS  262272      // int[17]
#define WS_XBF      1048576ull                      // bf16[8192][1024]   16 MB
#define WS_H        (WS_XBF + 16777216ull)          // bf16[16384][768]   24 MB
#define WS_WGT      (WS_H + 25165824ull)            // bf16[E][F][D]      24 MB
#define WS_WUT      (WS_WGT + 25165824ull)          // bf16[E][F][D]      24 MB
#define WS_WDT      (WS_WUT + 25165824ull)          // bf16[E][D][F]      24 MB
#define WS_O        (WS_WDT + 25165824ull)          // f32[16384][1024]   64 MB (optional)
#define WS_NEED_O   (WS_O + 67108864ull)

__device__ __forceinline__ unsigned short f2bf(float f) {
  union { float f; unsigned int u; } v; v.f = f;
  unsigned int r = v.u + 0x7fffu + ((v.u >> 16) & 1u);
  return (unsigned short)(r >> 16);
}

__device__ __forceinline__ void gld16(const void* g, void* l) {
  __builtin_amdgcn_global_load_lds((const __attribute__((address_space(1))) unsigned int*)g,
                                   (__attribute__((address_space(3))) unsigned int*)l, 16, 0, 0);
}

// ---------------- 1. hidden fp32 -> bf16 ----------------
__global__ void k_convert_x(const float* __restrict__ x, unsigned short* __restrict__ xb) {
  int i = blockIdx.x * blockDim.x + threadIdx.x;
  float4 v = ((const float4*)x)[i];
  ushort4 o;
  o.x = f2bf(v.x); o.y = f2bf(v.y); o.z = f2bf(v.z); o.w = f2bf(v.w);
  ((ushort4*)xb)[i] = o;
}

// ---------------- 1b. weight transpose+convert: WT[e][c][r] = bf16(W[e][r][c]) ----------------
__global__ __launch_bounds__(256) void k_wt(const float* __restrict__ W,
                                            unsigned short* __restrict__ WT,
                                            int R, int C) {
  __shared__ float t[64][68];
  int e = blockIdx.z;
  int r0 = blockIdx.y * 64, c0 = blockIdx.x * 64;
  int tid = threadIdx.x;
  int rr = tid >> 2, cc = (tid & 3) * 16;
  const float* src = W + (size_t)e * R * C + (size_t)(r0 + rr) * C + c0 + cc;
  float4 v0 = *(const float4*)(src);
  float4 v1 = *(const float4*)(src + 4);
  float4 v2 = *(const float4*)(src + 8);
  float4 v3 = *(const float4*)(src + 12);
  *(float4*)&t[rr][cc]      = v0;
  *(float4*)&t[rr][cc + 4]  = v1;
  *(float4*)&t[rr][cc + 8]  = v2;
  *(float4*)&t[rr][cc + 12] = v3;
  __syncthreads();
  int fr = tid >> 2, dd = (tid & 3) * 16;
  union { unsigned short s[16]; uint4 v[2]; } o;
  #pragma unroll
  for (int j = 0; j < 16; j++) o.s[j] = f2bf(t[dd + j][fr]);
  unsigned short* dst = WT + (size_t)e * C * R + (size_t)(c0 + fr) * R + r0 + dd;
  *(uint4*)dst = o.v[0];
  *((uint4*)dst + 1) = o.v[1];
}

// ---------------- 2. router ----------------
__global__ __launch_bounds__(256) void k_router(
    const float* __restrict__ X, const float* __restrict__ Wr,
    int* __restrict__ topk_idx, float* __restrict__ topk_w,
    int* __restrict__ counts, float* __restrict__ prob_sum)
{
  int tid = threadIdx.x, lane = tid & 63, wid = tid >> 6;
  int wave_global = blockIdx.x * 4 + wid;
  int q = lane >> 4, e = lane & 15;
  float pacc = 0.f; int cacc = 0;

  for (int i = 0; i < 4; i++) {
    int t = wave_global * 4 + i;
    const float* x = X + (size_t)t * DDIM + q * 256;
    const float* w = Wr + q * 256 * ENUM + e;
    double a0 = 0.0, a1 = 0.0;
    #pragma unroll 4
    for (int j = 0; j < 256; j += 2) {
      a0 += (double)x[j] * (double)w[j * ENUM];
      a1 += (double)x[j + 1] * (double)w[(j + 1) * ENUM];
    }
    double acc = a0 + a1;
    acc += __shfl_xor(acc, 16, 64);
    acc += __shfl_xor(acc, 32, 64);
    float logit = (float)acc;

    float m = logit;
    for (int d = 1; d < 16; d <<= 1) m = fmaxf(m, __shfl_xor(m, d, 64));
    float p = expf(logit - m);
    float s = p;
    for (int d = 1; d < 16; d <<= 1) s += __shfl_xor(s, d, 64);
    p = p / s;

    float p1 = p; int e1 = e;
    for (int d = 1; d < 16; d <<= 1) {
      float op = __shfl_xor(p1, d, 64); int oe = __shfl_xor(e1, d, 64);
      if (op > p1 || (op == p1 && oe < e1)) { p1 = op; e1 = oe; }
    }
    float px = (e == e1) ? -1.f : p;
    float p2 = px; int e2 = e;
    for (int d = 1; d < 16; d <<= 1) {
      float op = __shfl_xor(p2, d, 64); int oe = __shfl_xor(e2, d, 64);
      if (op > p2 || (op == p2 && oe < e2)) { p2 = op; e2 = oe; }
    }
    float den = fmaxf(p1 + p2, 1e-9f);
    if (lane == 0) {
      topk_idx[2 * t]     = e1; topk_idx[2 * t + 1] = e2;
      topk_w[2 * t]       = p1 / den; topk_w[2 * t + 1] = p2 / den;
    }
    if (lane < 16) { pacc += p; cacc += (e1 == e) + (e2 == e); }
  }
  __shared__ float sp[16]; __shared__ int sc[16];
  if (tid < 16) { sp[tid] = 0.f; sc[tid] = 0; }
  __syncthreads();
  if (lane < 16) { atomicAdd(&sp[e], pacc); atomicAdd(&sc[e], cacc); }
  __syncthreads();
  if (tid < 16) { atomicAdd(&prob_sum[tid], sp[tid]); atomicAdd(&counts[tid], sc[tid]); }
}

// ---------------- 3. deterministic per-expert slot lists ----------------
__global__ __launch_bounds__(256) void k_build_lists(
    const int* __restrict__ topk_idx, const int* __restrict__ counts,
    int* __restrict__ offsets, int* __restrict__ rows, int* __restrict__ row_of)
{
  int e = blockIdx.x;
  int base = 0;
  for (int i = 0; i < e; i++) base += counts[i];
  if (threadIdx.x == 0) {
    offsets[e] = base;
    if (e == 15) offsets[16] = base + counts[15];
  }
  __shared__ int wave_tot[4];
  int lane = threadIdx.x & 63, wid = threadIdx.x >> 6;
  int running = 0;
  for (int chunk = 0; chunk < NSLOT; chunk += 256) {
    int s = chunk + threadIdx.x;
    bool match = (topk_idx[s] == e);
    unsigned long long mask = __ballot(match);
    int wpre = __popcll(mask & ((1ull << lane) - 1ull));
    if (lane == 0) wave_tot[wid] = __popcll(mask);
    __syncthreads();
    int prefix = running;
    for (int w = 0; w < wid; w++) prefix += wave_tot[w];
    if (match) { int pos = base + prefix + wpre; rows[pos] = s; row_of[s] = pos; }
    running += wave_tot[0] + wave_tot[1] + wave_tot[2] + wave_tot[3];
    __syncthreads();
  }
}

// ---------------- 4. fused gate+up grouped GEMM (global_load_lds staging) ----------------
// tile 128(M) x 128(N of F) x 64(K of D); 8 waves (2m x 4n); wave tile 64x32
__global__ __launch_bounds__(512) void k_gateup(
    const unsigned short* __restrict__ Xbf, const unsigned short* __restrict__ WgT,
    const unsigned short* __restrict__ WuT, const int* __restrict__ counts,
    const int* __restrict__ offsets, const int* __restrict__ rows,
    unsigned short* __restrict__ H)
{
  const int e = blockIdx.z;
  const int cnt = counts[e];
  const int mt = blockIdx.y;
  if (mt * 128 >= cnt) return;
  const int nt = blockIdx.x;                 // 0..5
  const int base = offsets[e];

  __shared__ __align__(16) unsigned char sA[128 * 64 * 2];
  __shared__ __align__(16) unsigned char sBg[128 * 64 * 2];
  __shared__ __align__(16) unsigned char sBu[128 * 64 * 2];
  __shared__ int sTok[128];

  const int tid = threadIdx.x;
  const int lane = tid & 63;
  const int wid = tid >> 6;
  const int wm = wid >> 2, wn = wid & 3;
  const int q = lane >> 4, c = lane & 15;

  if (tid < 128) {
    int r = mt * 128 + tid;
    if (r >= cnt) r = cnt - 1;
    sTok[tid] = rows[base + r];
  }
  __syncthreads();

  // staging geometry: wave w instr i covers rows w*16+i*8 .. +7; lane -> row w*16+i*8+(l>>3)
  const int rstg0 = wid * 16 + (lane >> 3);
  const int rstg1 = rstg0 + 8;
  // source chunk pre-swizzle: LDS is linear; content permuted so swizzled reads see row-major
  const int colSw = (((lane & 7) << 4) ^ ((lane >> 3) << 4)) >> 1;  // in ushorts
  const unsigned short* tokp0 = Xbf + (size_t)(sTok[rstg0] >> 1) * DDIM + colSw;
  const unsigned short* tokp1 = Xbf + (size_t)(sTok[rstg1] >> 1) * DDIM + colSw;
  const unsigned short* wg0 = WgT + ((size_t)e * FDIM + nt * 128 + rstg0) * DDIM + colSw;
  const unsigned short* wg1 = WgT + ((size_t)e * FDIM + nt * 128 + rstg1) * DDIM + colSw;
  const unsigned short* wu0 = WuT + ((size_t)e * FDIM + nt * 128 + rstg0) * DDIM + colSw;
  const unsigned short* wu1 = WuT + ((size_t)e * FDIM + nt * 128 + rstg1) * DDIM + colSw;
  unsigned char* ldsA0 = sA  + wid * 2048;
  unsigned char* ldsA1 = sA  + wid * 2048 + 1024;
  unsigned char* ldsG0 = sBg + wid * 2048;
  unsigned char* ldsG1 = sBg + wid * 2048 + 1024;
  unsigned char* ldsU0 = sBu + wid * 2048;
  unsigned char* ldsU1 = sBu + wid * 2048 + 1024;

  f32x4 accg[4][2], accu[4][2];
  #pragma unroll
  for (int i = 0; i < 4; i++)
    #pragma unroll
    for (int j = 0; j < 2; j++) { accg[i][j] = (f32x4)(0.f); accu[i][j] = (f32x4)(0.f); }

  for (int kt = 0; kt < DDIM / 64; kt++) {
    const int ko = kt * 64;
    gld16(tokp0 + ko, ldsA0);
    gld16(tokp1 + ko, ldsA1);
    gld16(wg0 + ko, ldsG0);
    gld16(wg1 + ko, ldsG1);
    gld16(wu0 + ko, ldsU0);
    gld16(wu1 + ko, ldsU1);
    __syncthreads();
    #pragma unroll
    for (int kk = 0; kk < 2; kk++) {
      short8 af[4];
      #pragma unroll
      for (int mf = 0; mf < 4; mf++) {
        int row = wm * 64 + mf * 16 + c;
        af[mf] = *(const short8*)(sA + ((row * 128 + kk * 64 + q * 16) ^ ((row & 7) << 4)));
      }
      #pragma unroll
      for (int nf = 0; nf < 2; nf++) {
        int col = wn * 32 + nf * 16 + c;
        int b = (col * 128 + kk * 64 + q * 16) ^ ((col & 7) << 4);
        short8 bg = *(const short8*)(sBg + b);
        short8 bu = *(const short8*)(sBu + b);
        #pragma unroll
        for (int mf = 0; mf < 4; mf++) {
          accg[mf][nf] = __builtin_amdgcn_mfma_f32_16x16x32_bf16(af[mf], bg, accg[mf][nf], 0, 0, 0);
          accu[mf][nf] = __builtin_amdgcn_mfma_f32_16x16x32_bf16(af[mf], bu, accu[mf][nf], 0, 0, 0);
        }
      }
    }
    __syncthreads();
  }
  #pragma unroll
  for (int mf = 0; mf < 4; mf++)
    #pragma unroll
    for (int nf = 0; nf < 2; nf++)
      #pragma unroll
      for (int r = 0; r < 4; r++) {
        int row = wm * 64 + mf * 16 + q * 4 + r;
        int gr = mt * 128 + row;
        if (gr < cnt) {
          int col = wn * 32 + nf * 16 + c;
          float g = accg[mf][nf][r], u = accu[mf][nf][r];
          float sv = g / (1.0f + __expf(-g));
          H[(size_t)(base + gr) * FDIM + nt * 128 + col] = f2bf(sv * u);
        }
      }
}

// ---------------- 5. down grouped GEMM ----------------
// MODE 0: store fp32 O;  MODE 1: weighted atomicAdd into out (out pre-zeroed)
template <int MODE>
__global__ __launch_bounds__(512) void k_down(
    const unsigned short* __restrict__ H, const unsigned short* __restrict__ WdT,
    const int* __restrict__ counts, const int* __restrict__ offsets,
    const int* __restrict__ rows, const float* __restrict__ topk_w,
    float* __restrict__ O, float* __restrict__ out)
{
  const int e = blockIdx.z;
  const int cnt = counts[e];
  const int mt = blockIdx.y;
  if (mt * 128 >= cnt) return;
  const int nt = blockIdx.x;                 // 0..7
  const int base = offsets[e];

  __shared__ __align__(16) unsigned char sA[128 * 64 * 2];
  __shared__ __align__(16) unsigned char sB[128 * 64 * 2];
  __shared__ int sTk[128];
  __shared__ float sW[128];

  const int tid = threadIdx.x;
  const int lane = tid & 63;
  const int wid = tid >> 6;
  const int wm = wid >> 2, wn = wid & 3;
  const int q = lane >> 4, c = lane & 15;

  if (MODE == 1 && tid < 128) {
    int r = mt * 128 + tid;
    if (r >= cnt) r = cnt - 1;
    int s = rows[base + r];
    sTk[tid] = s >> 1;
    sW[tid] = topk_w[s];
  }
  if (MODE == 1) __syncthreads();

  const int rstg0 = wid * 16 + (lane >> 3);
  const int rstg1 = rstg0 + 8;
  const int colSw = (((lane & 7) << 4) ^ ((lane >> 3) << 4)) >> 1;
  int ga0 = base + mt * 128 + rstg0; if (ga0 > NSLOT - 1) ga0 = NSLOT - 1;
  int ga1 = base + mt * 128 + rstg1; if (ga1 > NSLOT - 1) ga1 = NSLOT - 1;
  const unsigned short* hp0 = H + (size_t)ga0 * FDIM + colSw;
  const unsigned short* hp1 = H + (size_t)ga1 * FDIM + colSw;
  const unsigned short* wd0 = WdT + ((size_t)e * DDIM + nt * 128 + rstg0) * FDIM + colSw;
  const unsigned short* wd1 = WdT + ((size_t)e * DDIM + nt * 128 + rstg1) * FDIM + colSw;
  unsigned char* ldsA0 = sA + wid * 2048;
  unsigned char* ldsA1 = sA + wid * 2048 + 1024;
  unsigned char* ldsB0 = sB + wid * 2048;
  unsigned char* ldsB1 = sB + wid * 2048 + 1024;

  f32x4 acc[4][2];
  #pragma unroll
  for (int i = 0; i < 4; i++)
    #pragma unroll
    for (int j = 0; j < 2; j++) acc[i][j] = (f32x4)(0.f);

  for (int kt = 0; kt < FDIM / 64; kt++) {
    const int ko = kt * 64;
    gld16(hp0 + ko, ldsA0);
    gld16(hp1 + ko, ldsA1);
    gld16(wd0 + ko, ldsB0);
    gld16(wd1 + ko, ldsB1);
    __syncthreads();
    #pragma unroll
    for (int kk = 0; kk < 2; kk++) {
      short8 af[4];
      #pragma unroll
      for (int mf = 0; mf < 4; mf++) {
        int row = wm * 64 + mf * 16 + c;
        af[mf] = *(const short8*)(sA + ((row * 128 + kk * 64 + q * 16) ^ ((row & 7) << 4)));
      }
      #pragma unroll
      for (int nf = 0; nf < 2; nf++) {
        int col = wn * 32 + nf * 16 + c;
        short8 bf = *(const short8*)(sB + ((col * 128 + kk * 64 + q * 16) ^ ((col & 7) << 4)));
        #pragma unroll
        for (int mf = 0; mf < 4; mf++)
          acc[mf][nf] = __builtin_amdgcn_mfma_f32_16x16x32_bf16(af[mf], bf, acc[mf][nf], 0, 0, 0);
      }
    }
    __syncthreads();
  }
  #pragma unroll
  for (int mf = 0; mf < 4; mf++)
    #pragma unroll
    for (int nf = 0; nf < 2; nf++)
      #pragma unroll
      for (int r = 0; r < 4; r++) {
        int row = wm * 64 + mf * 16 + q * 4 + r;
        int gr = mt * 128 + row;
        if (gr < cnt) {
          int col = wn * 32 + nf * 16 + c;
          if (MODE == 0) {
            O[(size_t)(base + gr) * DDIM + nt * 128 + col] = acc[mf][nf][r];
          } else {
            atomicAdd(&out[(size_t)sTk[row] * DDIM + nt * 128 + col], sW[row] * acc[mf][nf][r]);
          }
        }
      }
}

// ---------------- 6. combine top-2 (MODE 0 only) ----------------
__global__ __launch_bounds__(256) void k_combine(
    const float* __restrict__ O, const int* __restrict__ row_of,
    const float* __restrict__ topk_w, float* __restrict__ out)
{
  int t = blockIdx.x;
  int r0 = row_of[2 * t], r1 = row_of[2 * t + 1];
  float w0 = topk_w[2 * t], w1 = topk_w[2 * t + 1];
  int d = threadIdx.x * 4;
  float4 a = *(const float4*)(O + (size_t)r0 * DDIM + d);
  float4 b = *(const float4*)(O + (size_t)r1 * DDIM + d);
  float4 o;
  o.x = w0 * a.x + w1 * b.x; o.y = w0 * a.y + w1 * b.y;
  o.z = w0 * a.z + w1 * b.z; o.w = w0 * a.w + w1 * b.w;
  *(float4*)(out + (size_t)t * DDIM + d) = o;
}

// ---------------- 7. aux loss ----------------
__global__ void k_aux(const int* __restrict__ counts, const float* __restrict__ prob_sum,
                      float* __restrict__ out_aux) {
  if (threadIdx.x == 0) {
    float s = 0.f;
    for (int e = 0; e < ENUM; e++)
      s += ((float)counts[e] / (float)NTOK) * (prob_sum[e] / (float)NTOK);
    out_aux[0] = 0.001f * (float)ENUM * s;
  }
}

extern "C" void kernel_launch(void* const* d_in, const int* in_sizes, int n_in,
                              void* d_out, int out_size, void* d_ws, size_t ws_size,
                              hipStream_t stream) {
  const float* X  = (const float*)d_in[0];
  const float* Wg = (const float*)d_in[1];
  const float* Wu = (const float*)d_in[2];
  const float* Wd = (const float*)d_in[3];
  const float* Wr = (const float*)d_in[4];
  float* out = (float*)d_out;

  char* ws = (char*)d_ws;
  int*   topk_idx = (int*)(ws + WS_TOPK_IDX);
  float* topk_w   = (float*)(ws + WS_TOPK_W);
  int*   rows     = (int*)(ws + WS_ROWS);
  int*   row_of   = (int*)(ws + WS_ROW_OF);
  int*   counts   = (int*)(ws + WS_COUNTS);
  float* prob_sum = (float*)(ws + WS_PROB);
  int*   offsets  = (int*)(ws + WS_OFFSETS);
  unsigned short* Xbf = (unsigned short*)(ws + WS_XBF);
  unsigned short* H   = (unsigned short*)(ws + WS_H);
  unsigned short* WgT = (unsigned short*)(ws + WS_WGT);
  unsigned short* WuT = (unsigned short*)(ws + WS_WUT);
  unsigned short* WdT = (unsigned short*)(ws + WS_WDT);
  float* O            = (float*)(ws + WS_O);

  const bool useO = (ws_size >= WS_NEED_O);

  hipMemsetAsync(ws + WS_COUNTS, 0, 128, stream);
  if (!useO) hipMemsetAsync(d_out, 0, (size_t)out_size * 4, stream);

  k_convert_x<<<8192, 256, 0, stream>>>(X, Xbf);
  k_wt<<<dim3(FDIM / 64, DDIM / 64, ENUM), 256, 0, stream>>>(Wg, WgT, DDIM, FDIM);
  k_wt<<<dim3(FDIM / 64, DDIM / 64, ENUM), 256, 0, stream>>>(Wu, WuT, DDIM, FDIM);
  k_wt<<<dim3(DDIM / 64, FDIM / 64, ENUM), 256, 0, stream>>>(Wd, WdT, FDIM, DDIM);
  k_router<<<512, 256, 0, stream>>>(X, Wr, topk_idx, topk_w, counts, prob_sum);
  k_build_lists<<<16, 256, 0, stream>>>(topk_idx, counts, offsets, rows, row_of);
  k_gateup<<<dim3(6, 64, 16), 512, 0, stream>>>(Xbf, WgT, WuT, counts, offsets, rows, H);
  if (useO) {
    k_down<0><<<dim3(8, 64, 16), 512, 0, stream>>>(H, WdT, counts, offsets, rows, topk_w, O, out);
    k_combine<<<8192, 256, 0, stream>>>(O, row_of, topk_w, out);
  } else {
    k_down<1><<<dim3(8, 64, 16), 512, 0, stream>>>(H, WdT, counts, offsets, rows, topk_w, O, out);
  }
  k_aux<<<1, 64, 0, stream>>>(counts, prob_sum, out + (size_t)NTOK * DDIM);
}

// Round 3
// 305.465 us; speedup vs baseline: 1.7673x; 1.0760x over previous
//
#include <hip/hip_runtime.h>

typedef __attribute__((ext_vector_type(8))) short short8;
typedef __attribute__((ext_vector_type(4))) float f32x4;

#define NTOK   8192
#define DDIM   1024
#define ENUM   16
#define FDIM   768
#define NSLOT  16384

// ---------- ws layout (bytes) ----------
#define WS_TOPK_IDX 0           // int[16384]
#define WS_TOPK_W   65536       // float[16384]
#define WS_ROWS     131072      // int[16384]
#define WS_ROW_OF   196608      // int[16384]
#define WS_COUNTS   262144      // int[16]
#define WS_PROB     262208      // float[16]
#define WS_OFFSETS  262272      // int[17]
#define WS_XBF      1048576ull                      // bf16[8192][1024]   16 MB
#define WS_H        (WS_XBF + 16777216ull)          // bf16[16384][768]   24 MB
#define WS_WGT      (WS_H + 25165824ull)            // bf16[E][F][D]      24 MB
#define WS_WUT      (WS_WGT + 25165824ull)          // bf16[E][F][D]      24 MB
#define WS_WDT      (WS_WUT + 25165824ull)          // bf16[E][D][F]      24 MB
#define WS_O        (WS_WDT + 25165824ull)          // bf16[16384][1024]  32 MB (optional)
#define WS_NEED_O   (WS_O + 33554432ull)

__device__ __forceinline__ unsigned short f2bf(float f) {
  union { float f; unsigned int u; } v; v.f = f;
  unsigned int r = v.u + 0x7fffu + ((v.u >> 16) & 1u);
  return (unsigned short)(r >> 16);
}
__device__ __forceinline__ float bf2f(unsigned short s) {
  union { unsigned int u; float f; } v; v.u = ((unsigned int)s) << 16;
  return v.f;
}

__device__ __forceinline__ void gld16(const void* g, void* l) {
  __builtin_amdgcn_global_load_lds((const __attribute__((address_space(1))) unsigned int*)g,
                                   (__attribute__((address_space(3))) unsigned int*)l, 16, 0, 0);
}

// ---------------- 1. hidden fp32 -> bf16 ----------------
__global__ void k_convert_x(const float* __restrict__ x, unsigned short* __restrict__ xb) {
  int i = blockIdx.x * blockDim.x + threadIdx.x;
  float4 v = ((const float4*)x)[i];
  ushort4 o;
  o.x = f2bf(v.x); o.y = f2bf(v.y); o.z = f2bf(v.z); o.w = f2bf(v.w);
  ((ushort4*)xb)[i] = o;
}

// ---------------- 1b. weight transpose+convert: WT[e][c][r] = bf16(W[e][r][c]) ----------------
__global__ __launch_bounds__(256) void k_wt(const float* __restrict__ W,
                                            unsigned short* __restrict__ WT,
                                            int R, int C) {
  __shared__ float t[64][68];
  int e = blockIdx.z;
  int r0 = blockIdx.y * 64, c0 = blockIdx.x * 64;
  int tid = threadIdx.x;
  int rr = tid >> 2, cc = (tid & 3) * 16;
  const float* src = W + (size_t)e * R * C + (size_t)(r0 + rr) * C + c0 + cc;
  float4 v0 = *(const float4*)(src);
  float4 v1 = *(const float4*)(src + 4);
  float4 v2 = *(const float4*)(src + 8);
  float4 v3 = *(const float4*)(src + 12);
  *(float4*)&t[rr][cc]      = v0;
  *(float4*)&t[rr][cc + 4]  = v1;
  *(float4*)&t[rr][cc + 8]  = v2;
  *(float4*)&t[rr][cc + 12] = v3;
  __syncthreads();
  int fr = tid >> 2, dd = (tid & 3) * 16;
  union { unsigned short s[16]; uint4 v[2]; } o;
  #pragma unroll
  for (int j = 0; j < 16; j++) o.s[j] = f2bf(t[dd + j][fr]);
  unsigned short* dst = WT + (size_t)e * C * R + (size_t)(c0 + fr) * R + r0 + dd;
  *(uint4*)dst = o.v[0];
  *((uint4*)dst + 1) = o.v[1];
}

// ---------------- 2. router ----------------
__global__ __launch_bounds__(256) void k_router(
    const float* __restrict__ X, const float* __restrict__ Wr,
    int* __restrict__ topk_idx, float* __restrict__ topk_w,
    int* __restrict__ counts, float* __restrict__ prob_sum)
{
  int tid = threadIdx.x, lane = tid & 63, wid = tid >> 6;
  int wave_global = blockIdx.x * 4 + wid;
  int q = lane >> 4, e = lane & 15;
  float pacc = 0.f; int cacc = 0;

  for (int i = 0; i < 4; i++) {
    int t = wave_global * 4 + i;
    const float* x = X + (size_t)t * DDIM + q * 256;
    const float* w = Wr + q * 256 * ENUM + e;
    double a0 = 0.0, a1 = 0.0;
    #pragma unroll 4
    for (int j = 0; j < 256; j += 2) {
      a0 += (double)x[j] * (double)w[j * ENUM];
      a1 += (double)x[j + 1] * (double)w[(j + 1) * ENUM];
    }
    double acc = a0 + a1;
    acc += __shfl_xor(acc, 16, 64);
    acc += __shfl_xor(acc, 32, 64);
    float logit = (float)acc;

    float m = logit;
    for (int d = 1; d < 16; d <<= 1) m = fmaxf(m, __shfl_xor(m, d, 64));
    float p = expf(logit - m);
    float s = p;
    for (int d = 1; d < 16; d <<= 1) s += __shfl_xor(s, d, 64);
    p = p / s;

    float p1 = p; int e1 = e;
    for (int d = 1; d < 16; d <<= 1) {
      float op = __shfl_xor(p1, d, 64); int oe = __shfl_xor(e1, d, 64);
      if (op > p1 || (op == p1 && oe < e1)) { p1 = op; e1 = oe; }
    }
    float px = (e == e1) ? -1.f : p;
    float p2 = px; int e2 = e;
    for (int d = 1; d < 16; d <<= 1) {
      float op = __shfl_xor(p2, d, 64); int oe = __shfl_xor(e2, d, 64);
      if (op > p2 || (op == p2 && oe < e2)) { p2 = op; e2 = oe; }
    }
    float den = fmaxf(p1 + p2, 1e-9f);
    if (lane == 0) {
      topk_idx[2 * t]     = e1; topk_idx[2 * t + 1] = e2;
      topk_w[2 * t]       = p1 / den; topk_w[2 * t + 1] = p2 / den;
    }
    if (lane < 16) { pacc += p; cacc += (e1 == e) + (e2 == e); }
  }
  __shared__ float sp[16]; __shared__ int sc[16];
  if (tid < 16) { sp[tid] = 0.f; sc[tid] = 0; }
  __syncthreads();
  if (lane < 16) { atomicAdd(&sp[e], pacc); atomicAdd(&sc[e], cacc); }
  __syncthreads();
  if (tid < 16) { atomicAdd(&prob_sum[tid], sp[tid]); atomicAdd(&counts[tid], sc[tid]); }
}

// ---------------- 3. deterministic per-expert slot lists ----------------
__global__ __launch_bounds__(256) void k_build_lists(
    const int* __restrict__ topk_idx, const int* __restrict__ counts,
    int* __restrict__ offsets, int* __restrict__ rows, int* __restrict__ row_of)
{
  int e = blockIdx.x;
  int base = 0;
  for (int i = 0; i < e; i++) base += counts[i];
  if (threadIdx.x == 0) {
    offsets[e] = base;
    if (e == 15) offsets[16] = base + counts[15];
  }
  __shared__ int wave_tot[4];
  int lane = threadIdx.x & 63, wid = threadIdx.x >> 6;
  int running = 0;
  for (int chunk = 0; chunk < NSLOT; chunk += 256) {
    int s = chunk + threadIdx.x;
    bool match = (topk_idx[s] == e);
    unsigned long long mask = __ballot(match);
    int wpre = __popcll(mask & ((1ull << lane) - 1ull));
    if (lane == 0) wave_tot[wid] = __popcll(mask);
    __syncthreads();
    int prefix = running;
    for (int w = 0; w < wid; w++) prefix += wave_tot[w];
    if (match) { int pos = base + prefix + wpre; rows[pos] = s; row_of[s] = pos; }
    running += wave_tot[0] + wave_tot[1] + wave_tot[2] + wave_tot[3];
    __syncthreads();
  }
}

// ---------------- 4. fused gate+up grouped GEMM (dbuf prefetch + XCD chunking) ----------------
// tile 128(M) x 128(N of F) x 64(K); 8 waves (2m x 4n); wave tile 64x32
// grid: 6144 linear; xcd=id&7 owns experts {2x,2x+1}; within-expert order mt-major
__global__ __launch_bounds__(512) void k_gateup(
    const unsigned short* __restrict__ Xbf, const unsigned short* __restrict__ WgT,
    const unsigned short* __restrict__ WuT, const int* __restrict__ counts,
    const int* __restrict__ offsets, const int* __restrict__ rows,
    unsigned short* __restrict__ H)
{
  const int id = blockIdx.x;
  const int xcd = id & 7;
  const int within = id >> 3;                // 0..767
  const int e = xcd * 2 + (within >= 384);
  const int rem = within - (within >= 384 ? 384 : 0);
  const int mt = rem / 6;
  const int nt = rem - mt * 6;

  const int cnt = counts[e];
  if (mt * 128 >= cnt) return;
  const int base = offsets[e];

  __shared__ __align__(16) unsigned char sA [2][128 * 64 * 2];
  __shared__ __align__(16) unsigned char sBg[2][128 * 64 * 2];
  __shared__ __align__(16) unsigned char sBu[2][128 * 64 * 2];
  __shared__ int sTok[128];

  const int tid = threadIdx.x;
  const int lane = tid & 63;
  const int wid = tid >> 6;
  const int wm = wid >> 2, wn = wid & 3;
  const int q = lane >> 4, c = lane & 15;

  if (tid < 128) {
    int r = mt * 128 + tid;
    if (r >= cnt) r = cnt - 1;
    sTok[tid] = rows[base + r];
  }
  __syncthreads();

  const int rstg0 = wid * 16 + (lane >> 3);
  const int rstg1 = rstg0 + 8;
  const int colSw = (((lane & 7) << 4) ^ ((lane >> 3) << 4)) >> 1;  // ushorts
  const unsigned short* tokp0 = Xbf + (size_t)(sTok[rstg0] >> 1) * DDIM + colSw;
  const unsigned short* tokp1 = Xbf + (size_t)(sTok[rstg1] >> 1) * DDIM + colSw;
  const unsigned short* wg0 = WgT + ((size_t)e * FDIM + nt * 128 + rstg0) * DDIM + colSw;
  const unsigned short* wg1 = WgT + ((size_t)e * FDIM + nt * 128 + rstg1) * DDIM + colSw;
  const unsigned short* wu0 = WuT + ((size_t)e * FDIM + nt * 128 + rstg0) * DDIM + colSw;
  const unsigned short* wu1 = WuT + ((size_t)e * FDIM + nt * 128 + rstg1) * DDIM + colSw;
  const int woff = wid * 2048;

  f32x4 accg[4][2], accu[4][2];
  #pragma unroll
  for (int i = 0; i < 4; i++)
    #pragma unroll
    for (int j = 0; j < 2; j++) { accg[i][j] = (f32x4)(0.f); accu[i][j] = (f32x4)(0.f); }

  // prologue stage kt=0 into buf 0
  {
    gld16(tokp0, sA[0] + woff);  gld16(tokp1, sA[0] + woff + 1024);
    gld16(wg0,   sBg[0] + woff); gld16(wg1,   sBg[0] + woff + 1024);
    gld16(wu0,   sBu[0] + woff); gld16(wu1,   sBu[0] + woff + 1024);
  }
  __syncthreads();

  int cur = 0;
  for (int kt = 0; kt < DDIM / 64; kt++) {
    if (kt + 1 < DDIM / 64) {                 // issue next-tile loads (overlap compute)
      const int ko = (kt + 1) * 64;
      const int nb = cur ^ 1;
      gld16(tokp0 + ko, sA[nb] + woff);  gld16(tokp1 + ko, sA[nb] + woff + 1024);
      gld16(wg0 + ko,   sBg[nb] + woff); gld16(wg1 + ko,   sBg[nb] + woff + 1024);
      gld16(wu0 + ko,   sBu[nb] + woff); gld16(wu1 + ko,   sBu[nb] + woff + 1024);
    }
    #pragma unroll
    for (int kk = 0; kk < 2; kk++) {
      short8 af[4];
      #pragma unroll
      for (int mf = 0; mf < 4; mf++) {
        int row = wm * 64 + mf * 16 + c;
        af[mf] = *(const short8*)(sA[cur] + ((row * 128 + kk * 64 + q * 16) ^ ((row & 7) << 4)));
      }
      #pragma unroll
      for (int nf = 0; nf < 2; nf++) {
        int col = wn * 32 + nf * 16 + c;
        int b = (col * 128 + kk * 64 + q * 16) ^ ((col & 7) << 4);
        short8 bg = *(const short8*)(sBg[cur] + b);
        short8 bu = *(const short8*)(sBu[cur] + b);
        #pragma unroll
        for (int mf = 0; mf < 4; mf++) {
          accg[mf][nf] = __builtin_amdgcn_mfma_f32_16x16x32_bf16(af[mf], bg, accg[mf][nf], 0, 0, 0);
          accu[mf][nf] = __builtin_amdgcn_mfma_f32_16x16x32_bf16(af[mf], bu, accu[mf][nf], 0, 0, 0);
        }
      }
    }
    __syncthreads();                          // vmcnt(0): staged next buf ready
    cur ^= 1;
  }

  #pragma unroll
  for (int mf = 0; mf < 4; mf++)
    #pragma unroll
    for (int nf = 0; nf < 2; nf++)
      #pragma unroll
      for (int r = 0; r < 4; r++) {
        int row = wm * 64 + mf * 16 + q * 4 + r;
        int gr = mt * 128 + row;
        if (gr < cnt) {
          int col = wn * 32 + nf * 16 + c;
          float g = accg[mf][nf][r], u = accu[mf][nf][r];
          float sv = g / (1.0f + __expf(-g));
          H[(size_t)(base + gr) * FDIM + nt * 128 + col] = f2bf(sv * u);
        }
      }
}

// ---------------- 5. down grouped GEMM (dbuf prefetch + XCD chunking) ----------------
// MODE 0: store bf16 O;  MODE 1: weighted atomicAdd into out (out pre-zeroed)
template <int MODE>
__global__ __launch_bounds__(512) void k_down(
    const unsigned short* __restrict__ H, const unsigned short* __restrict__ WdT,
    const int* __restrict__ counts, const int* __restrict__ offsets,
    const int* __restrict__ rows, const float* __restrict__ topk_w,
    unsigned short* __restrict__ O, float* __restrict__ out)
{
  const int id = blockIdx.x;
  const int xcd = id & 7;
  const int within = id >> 3;                // 0..1023
  const int e = xcd * 2 + (within >> 9);
  const int rem = within & 511;
  const int mt = rem >> 3;
  const int nt = rem & 7;

  const int cnt = counts[e];
  if (mt * 128 >= cnt) return;
  const int base = offsets[e];

  __shared__ __align__(16) unsigned char sA[2][128 * 64 * 2];
  __shared__ __align__(16) unsigned char sB[2][128 * 64 * 2];
  __shared__ int sTk[128];
  __shared__ float sW[128];

  const int tid = threadIdx.x;
  const int lane = tid & 63;
  const int wid = tid >> 6;
  const int wm = wid >> 2, wn = wid & 3;
  const int q = lane >> 4, c = lane & 15;

  if (MODE == 1 && tid < 128) {
    int r = mt * 128 + tid;
    if (r >= cnt) r = cnt - 1;
    int s = rows[base + r];
    sTk[tid] = s >> 1;
    sW[tid] = topk_w[s];
  }
  if (MODE == 1) __syncthreads();

  const int rstg0 = wid * 16 + (lane >> 3);
  const int rstg1 = rstg0 + 8;
  const int colSw = (((lane & 7) << 4) ^ ((lane >> 3) << 4)) >> 1;
  int ga0 = base + mt * 128 + rstg0; if (ga0 > NSLOT - 1) ga0 = NSLOT - 1;
  int ga1 = base + mt * 128 + rstg1; if (ga1 > NSLOT - 1) ga1 = NSLOT - 1;
  const unsigned short* hp0 = H + (size_t)ga0 * FDIM + colSw;
  const unsigned short* hp1 = H + (size_t)ga1 * FDIM + colSw;
  const unsigned short* wd0 = WdT + ((size_t)e * DDIM + nt * 128 + rstg0) * FDIM + colSw;
  const unsigned short* wd1 = WdT + ((size_t)e * DDIM + nt * 128 + rstg1) * FDIM + colSw;
  const int woff = wid * 2048;

  f32x4 acc[4][2];
  #pragma unroll
  for (int i = 0; i < 4; i++)
    #pragma unroll
    for (int j = 0; j < 2; j++) acc[i][j] = (f32x4)(0.f);

  {
    gld16(hp0, sA[0] + woff); gld16(hp1, sA[0] + woff + 1024);
    gld16(wd0, sB[0] + woff); gld16(wd1, sB[0] + woff + 1024);
  }
  __syncthreads();

  int cur = 0;
  for (int kt = 0; kt < FDIM / 64; kt++) {
    if (kt + 1 < FDIM / 64) {
      const int ko = (kt + 1) * 64;
      const int nb = cur ^ 1;
      gld16(hp0 + ko, sA[nb] + woff); gld16(hp1 + ko, sA[nb] + woff + 1024);
      gld16(wd0 + ko, sB[nb] + woff); gld16(wd1 + ko, sB[nb] + woff + 1024);
    }
    #pragma unroll
    for (int kk = 0; kk < 2; kk++) {
      short8 af[4];
      #pragma unroll
      for (int mf = 0; mf < 4; mf++) {
        int row = wm * 64 + mf * 16 + c;
        af[mf] = *(const short8*)(sA[cur] + ((row * 128 + kk * 64 + q * 16) ^ ((row & 7) << 4)));
      }
      #pragma unroll
      for (int nf = 0; nf < 2; nf++) {
        int col = wn * 32 + nf * 16 + c;
        short8 bf = *(const short8*)(sB[cur] + ((col * 128 + kk * 64 + q * 16) ^ ((col & 7) << 4)));
        #pragma unroll
        for (int mf = 0; mf < 4; mf++)
          acc[mf][nf] = __builtin_amdgcn_mfma_f32_16x16x32_bf16(af[mf], bf, acc[mf][nf], 0, 0, 0);
      }
    }
    __syncthreads();
    cur ^= 1;
  }

  #pragma unroll
  for (int mf = 0; mf < 4; mf++)
    #pragma unroll
    for (int nf = 0; nf < 2; nf++)
      #pragma unroll
      for (int r = 0; r < 4; r++) {
        int row = wm * 64 + mf * 16 + q * 4 + r;
        int gr = mt * 128 + row;
        if (gr < cnt) {
          int col = wn * 32 + nf * 16 + c;
          if (MODE == 0) {
            O[(size_t)(base + gr) * DDIM + nt * 128 + col] = f2bf(acc[mf][nf][r]);
          } else {
            atomicAdd(&out[(size_t)sTk[row] * DDIM + nt * 128 + col], sW[row] * acc[mf][nf][r]);
          }
        }
      }
}

// ---------------- 6. combine top-2 (MODE 0 only) ----------------
__global__ __launch_bounds__(128) void k_combine(
    const unsigned short* __restrict__ O, const int* __restrict__ row_of,
    const float* __restrict__ topk_w, float* __restrict__ out)
{
  int t = blockIdx.x;
  int r0 = row_of[2 * t], r1 = row_of[2 * t + 1];
  float w0 = topk_w[2 * t], w1 = topk_w[2 * t + 1];
  int d = threadIdx.x * 8;
  short8 a = *(const short8*)(O + (size_t)r0 * DDIM + d);
  short8 b = *(const short8*)(O + (size_t)r1 * DDIM + d);
  float4 o0, o1;
  float* po = (float*)&o0;
  #pragma unroll
  for (int j = 0; j < 8; j++) {
    float r = w0 * bf2f((unsigned short)a[j]) + w1 * bf2f((unsigned short)b[j]);
    if (j < 4) ((float*)&o0)[j] = r; else ((float*)&o1)[j - 4] = r;
  }
  (void)po;
  *(float4*)(out + (size_t)t * DDIM + d) = o0;
  *(float4*)(out + (size_t)t * DDIM + d + 4) = o1;
}

// ---------------- 7. aux loss ----------------
__global__ void k_aux(const int* __restrict__ counts, const float* __restrict__ prob_sum,
                      float* __restrict__ out_aux) {
  if (threadIdx.x == 0) {
    float s = 0.f;
    for (int e = 0; e < ENUM; e++)
      s += ((float)counts[e] / (float)NTOK) * (prob_sum[e] / (float)NTOK);
    out_aux[0] = 0.001f * (float)ENUM * s;
  }
}

extern "C" void kernel_launch(void* const* d_in, const int* in_sizes, int n_in,
                              void* d_out, int out_size, void* d_ws, size_t ws_size,
                              hipStream_t stream) {
  const float* X  = (const float*)d_in[0];
  const float* Wg = (const float*)d_in[1];
  const float* Wu = (const float*)d_in[2];
  const float* Wd = (const float*)d_in[3];
  const float* Wr = (const float*)d_in[4];
  float* out = (float*)d_out;

  char* ws = (char*)d_ws;
  int*   topk_idx = (int*)(ws + WS_TOPK_IDX);
  float* topk_w   = (float*)(ws + WS_TOPK_W);
  int*   rows     = (int*)(ws + WS_ROWS);
  int*   row_of   = (int*)(ws + WS_ROW_OF);
  int*   counts   = (int*)(ws + WS_COUNTS);
  float* prob_sum = (float*)(ws + WS_PROB);
  int*   offsets  = (int*)(ws + WS_OFFSETS);
  unsigned short* Xbf = (unsigned short*)(ws + WS_XBF);
  unsigned short* H   = (unsigned short*)(ws + WS_H);
  unsigned short* WgT = (unsigned short*)(ws + WS_WGT);
  unsigned short* WuT = (unsigned short*)(ws + WS_WUT);
  unsigned short* WdT = (unsigned short*)(ws + WS_WDT);
  unsigned short* O   = (unsigned short*)(ws + WS_O);

  const bool useO = (ws_size >= WS_NEED_O);

  hipMemsetAsync(ws + WS_COUNTS, 0, 128, stream);
  if (!useO) hipMemsetAsync(d_out, 0, (size_t)out_size * 4, stream);

  k_convert_x<<<8192, 256, 0, stream>>>(X, Xbf);
  k_wt<<<dim3(FDIM / 64, DDIM / 64, ENUM), 256, 0, stream>>>(Wg, WgT, DDIM, FDIM);
  k_wt<<<dim3(FDIM / 64, DDIM / 64, ENUM), 256, 0, stream>>>(Wu, WuT, DDIM, FDIM);
  k_wt<<<dim3(DDIM / 64, FDIM / 64, ENUM), 256, 0, stream>>>(Wd, WdT, FDIM, DDIM);
  k_router<<<512, 256, 0, stream>>>(X, Wr, topk_idx, topk_w, counts, prob_sum);
  k_build_lists<<<16, 256, 0, stream>>>(topk_idx, counts, offsets, rows, row_of);
  k_gateup<<<6144, 512, 0, stream>>>(Xbf, WgT, WuT, counts, offsets, rows, H);
  if (useO) {
    k_down<0><<<8192, 512, 0, stream>>>(H, WdT, counts, offsets, rows, topk_w, O, out);
    k_combine<<<8192, 128, 0, stream>>>(O, row_of, topk_w, out);
  } else {
    k_down<1><<<8192, 512, 0, stream>>>(H, WdT, counts, offsets, rows, topk_w, O, out);
  }
  k_aux<<<1, 64, 0, stream>>>(counts, prob_sum, out + (size_t)NTOK * DDIM);
}